// Round 1
// 593.048 us; speedup vs baseline: 1.0707x; 1.0707x over previous
//
#include <hip/hip_runtime.h>

// Problem constants (match reference file)
#define B_ 16
#define N_ 8192
#define M_ 2048
#define K_ 32
#define C_ 128

// out layout: pts [B,M,K,3] floats, then features [B,M,K,C] floats
#define PTS_ELEMS ((size_t)B_ * M_ * K_ * 3)   // 3,145,728

typedef float v4f __attribute__((ext_vector_type(4)));

// One thread per (b,m,k). K=32 groups align to 32-lane halves of a wave64,
// so max-over-K is a 5-step shuffle butterfly (xor masks 1..16 stay in-group).
__global__ void pts_kernel(const float* __restrict__ points,
                           const float* __restrict__ next_pts,
                           const int* __restrict__ indices,
                           float* __restrict__ out_pts) {
    int t = blockIdx.x * blockDim.x + threadIdx.x;   // flat over B*M*K
    // decompose: t = ((b*M + m)*K + k)
    int bm = t >> 5;              // / K_
    int m  = bm & (M_ - 1);
    int b  = bm >> 11;            // / M_

    int idx = indices[t];
    const float* p  = points   + ((size_t)b * N_ + idx) * 3;
    const float* nq = next_pts + ((size_t)b * M_ + m) * 3;

    float x = p[0] - nq[0];
    float y = p[1] - nq[1];
    float z = p[2] - nq[2];
    float sq = x * x + y * y + z * z;

    // max over the K=32 group (lanes 0-31 / 32-63 are distinct groups)
    float mx = sq;
    #pragma unroll
    for (int off = 1; off <= 16; off <<= 1) {
        float o = __shfl_xor(mx, off, 64);
        mx = fmaxf(mx, o);
    }
    float maxi = sqrtf(mx);
    if (maxi == 0.0f) maxi = 1.0f;

    float* o = out_pts + (size_t)t * 3;
    o[0] = x / maxi;
    o[1] = y / maxi;
    o[2] = z / maxi;
}

// One block per (b,m) group: K*C floats = 1024 float4 = 256 threads x 4.
// Each thread owns one c4 column (tid&31) and 4 of the K=32 rows
// (tid>>5 + {0,8,16,24}) -> 4 independent gather chains (MLP=4),
// 4x fewer waves than 1-f4-per-thread, and all gathers stay inside one
// batch slice (4.19 MB, ~L2-resident).
// Feature output is written with NON-TEMPORAL stores so the 537 MB write
// stream does not evict the gathered input rows from the per-XCD L2.
__global__ __launch_bounds__(256) void feat_kernel(const float* __restrict__ input,
                                                   const int* __restrict__ indices,
                                                   v4f* __restrict__ out_feat) {
    int bm  = blockIdx.x;           // (b*M + m), 0 .. B*M-1
    int b   = bm >> 11;             // / M_
    int tid = threadIdx.x;
    int c4  = tid & 31;             // C/4 = 32 columns of float4
    int k0  = tid >> 5;             // 0..7

    const int* idxp  = indices + (size_t)bm * K_;
    const v4f* in_b  = (const v4f*)input + (size_t)b * ((size_t)N_ * (C_ / 4));
    v4f*       ob    = out_feat + (size_t)bm * (K_ * (C_ / 4));

    int i0 = idxp[k0];
    int i1 = idxp[k0 + 8];
    int i2 = idxp[k0 + 16];
    int i3 = idxp[k0 + 24];

    // 4 independent 16B gathers (cached: input rows are reused ~8x on average)
    v4f v0 = in_b[(size_t)i0 * (C_ / 4) + c4];
    v4f v1 = in_b[(size_t)i1 * (C_ / 4) + c4];
    v4f v2 = in_b[(size_t)i2 * (C_ / 4) + c4];
    v4f v3 = in_b[(size_t)i3 * (C_ / 4) + c4];

    // streaming (non-temporal) stores: bypass/evict-first in L2
    __builtin_nontemporal_store(v0, ob + ((k0     ) * (C_ / 4) + c4));
    __builtin_nontemporal_store(v1, ob + ((k0 +  8) * (C_ / 4) + c4));
    __builtin_nontemporal_store(v2, ob + ((k0 + 16) * (C_ / 4) + c4));
    __builtin_nontemporal_store(v3, ob + ((k0 + 24) * (C_ / 4) + c4));
}

extern "C" void kernel_launch(void* const* d_in, const int* in_sizes, int n_in,
                              void* d_out, int out_size, void* d_ws, size_t ws_size,
                              hipStream_t stream) {
    const float* input    = (const float*)d_in[0];
    const float* points   = (const float*)d_in[1];
    const float* next_pts = (const float*)d_in[2];
    const int*   indices  = (const int*)d_in[3];
    float* out = (float*)d_out;

    float* out_pts  = out;
    v4f*   out_feat = (v4f*)(out + PTS_ELEMS);  // 12.58 MB offset, 16B aligned

    // pts: B*M*K = 1,048,576 threads
    {
        int total = B_ * M_ * K_;
        int block = 256;
        int grid = total / block;   // 4096
        pts_kernel<<<grid, block, 0, stream>>>(points, next_pts, indices, out_pts);
    }
    // features: one block per (b,m) -> 32768 blocks of 256 threads
    {
        int grid = B_ * M_;         // 32768
        int block = 256;
        feat_kernel<<<grid, block, 0, stream>>>(input, indices, out_feat);
    }
}